// Round 1
// baseline (131.391 us; speedup 1.0000x reference)
//
#include <hip/hip_runtime.h>
#include <math.h>

#define TPB 256
#define CH  128

// ---------------------------------------------------------------------------
// Kernel 1: partial contraction. Each thread owns one column j of K.
// Block (bx, by) processes j-tile bx and obs-chunk by, accumulating
//   s0 = sum_i alpha0[i] * M(i,j),  s1 = sum_i alpha1[i] * M(i,j)
// per domain segment (transfer factor hoisted), then atomicAdds into f01.
// ---------------------------------------------------------------------------
__global__ __launch_bounds__(TPB) void matern_partial(
    const float* __restrict__ xobs, const float* __restrict__ x,
    const float* __restrict__ alpha0, const float* __restrict__ alpha1,
    const float* __restrict__ tfl, const float* __restrict__ rawls,
    const int* __restrict__ rngo, const int* __restrict__ rngx,
    float* __restrict__ f01, int n_obs, int n_x)
{
    __shared__ float  s_xo[CH][16];   // scaled xobs rows
    __shared__ float4 s_meta[CH];     // {|xo|^2, alpha0, alpha1, 0}

    const int tid = threadIdx.x;
    const int j   = blockIdx.x * TPB + tid;
    const int c0  = blockIdx.y * CH;
    const int c1  = min(c0 + CH, n_obs);
    const int clen = c1 - c0;

    // lengthscale = softplus(raw)
    const float r      = rawls[0];
    const float ls     = fmaxf(r, 0.0f) + log1pf(__expf(-fabsf(r)));
    const float inv_ls = 1.0f / ls;

    // ---- stage scaled xobs chunk into LDS (coalesced) ----
    for (int idx = tid; idx < clen * 16; idx += TPB) {
        const int ii = idx >> 4, k = idx & 15;
        s_xo[ii][k] = xobs[(c0 + ii) * 16 + k] * inv_ls;
    }
    __syncthreads();
    // ---- per-row norm + alphas ----
    for (int ii = tid; ii < clen; ii += TPB) {
        float s = 0.f;
        #pragma unroll
        for (int k = 0; k < 16; ++k) { const float v = s_xo[ii][k]; s = fmaf(v, v, s); }
        s_meta[ii] = make_float4(s, alpha0[c0 + ii], alpha1[c0 + ii], 0.f);
    }
    __syncthreads();

    // ---- per-thread column data ----
    const bool active = (j < n_x);
    const int  jj     = active ? j : 0;
    float xj[16];
    float nxj = 0.f;
    #pragma unroll
    for (int k = 0; k < 16; ++k) {
        const float v = x[jj * 16 + k] * inv_ls;
        xj[k] = v;
        nxj = fmaf(v, v, nxj);
    }

    // transfer factor row for this column's domain
    const float t0 = 1.f / (1.f + __expf(-tfl[0]));   // F[0][1]
    const float t1 = 1.f / (1.f + __expf(-tfl[1]));   // F[0][2]
    const float t2 = 1.f / (1.f + __expf(-tfl[2]));   // F[1][2]
    const int dxj = (jj >= rngx[2] ? 1 : 0) + (jj >= rngx[4] ? 1 : 0);
    const float fd0 = (dxj == 0) ? 1.f : ((dxj == 1) ? t0 : t1);
    const float fd1 = (dxj == 0) ? t0  : ((dxj == 1) ? 1.f : t2);
    const float fd2 = (dxj == 0) ? t1  : ((dxj == 1) ? t2  : 1.f);

    const float S5  = 2.2360679774997896f;   // sqrt(5)
    const float C53 = 5.0f / 3.0f;

    float acc0 = 0.f, acc1 = 0.f;

    #pragma unroll
    for (int dom = 0; dom < 3; ++dom) {
        const int ds = max(c0, rngo[dom * 2 + 0]);
        const int de = min(c1, rngo[dom * 2 + 1]);
        float s0 = 0.f, s1 = 0.f;
        #pragma unroll 2
        for (int i = ds; i < de; ++i) {
            const int ii = i - c0;
            const float4* xr = (const float4*)&s_xo[ii][0];   // broadcast reads
            const float4 p0 = xr[0], p1 = xr[1], p2 = xr[2], p3 = xr[3];
            const float4 meta = s_meta[ii];

            // 4 independent fma chains -> tree combine (latency hiding)
            float q0 = xj[0] * p0.x;
            q0 = fmaf(xj[1], p0.y, q0); q0 = fmaf(xj[2], p0.z, q0); q0 = fmaf(xj[3], p0.w, q0);
            float q1 = xj[4] * p1.x;
            q1 = fmaf(xj[5], p1.y, q1); q1 = fmaf(xj[6], p1.z, q1); q1 = fmaf(xj[7], p1.w, q1);
            float q2 = xj[8] * p2.x;
            q2 = fmaf(xj[9], p2.y, q2); q2 = fmaf(xj[10], p2.z, q2); q2 = fmaf(xj[11], p2.w, q2);
            float q3 = xj[12] * p3.x;
            q3 = fmaf(xj[13], p3.y, q3); q3 = fmaf(xj[14], p3.z, q3); q3 = fmaf(xj[15], p3.w, q3);
            const float dot = (q0 + q1) + (q2 + q3);

            float sq = fmaf(-2.f, dot, meta.x + nxj);
            sq = fmaxf(sq, 1e-12f);
            const float d    = sqrtf(sq);
            const float s5d  = S5 * d;
            const float poly = fmaf(C53, sq, 1.0f) + s5d;
            const float e    = __expf(-s5d);
            const float m    = poly * e;
            s0 = fmaf(meta.y, m, s0);
            s1 = fmaf(meta.z, m, s1);
        }
        const float fd = (dom == 0) ? fd0 : ((dom == 1) ? fd1 : fd2);
        acc0 = fmaf(fd, s0, acc0);
        acc1 = fmaf(fd, s1, acc1);
    }

    if (active) {
        atomicAdd(&f01[j], acc0);
        atomicAdd(&f01[n_x + j], acc1);
    }
}

// ---------------------------------------------------------------------------
// Kernel 2: out[j] = w[j]*f0[j] + (1-w[j])*f1[j]
// ---------------------------------------------------------------------------
__global__ void combine_out(const float* __restrict__ w,
                            const float* __restrict__ f01,
                            float* __restrict__ out, int n_x)
{
    const int j = blockIdx.x * 256 + threadIdx.x;
    if (j < n_x) {
        const float wv = w[j];
        out[j] = wv * f01[j] + (1.f - wv) * f01[n_x + j];
    }
}

extern "C" void kernel_launch(void* const* d_in, const int* in_sizes, int n_in,
                              void* d_out, int out_size, void* d_ws, size_t ws_size,
                              hipStream_t stream)
{
    const float* xobs = (const float*)d_in[0];
    const float* x    = (const float*)d_in[1];
    const float* w    = (const float*)d_in[2];
    const float* a0   = (const float*)d_in[3];
    const float* a1   = (const float*)d_in[4];
    const float* tfl  = (const float*)d_in[5];
    const float* rls  = (const float*)d_in[6];
    const int*   rngo = (const int*)d_in[7];
    const int*   rngx = (const int*)d_in[8];

    const int n_obs = in_sizes[0] / 16;
    const int n_x   = in_sizes[1] / 16;

    float* f01 = (float*)d_ws;   // [2][n_x] partial sums
    hipMemsetAsync(f01, 0, sizeof(float) * 2 * (size_t)n_x, stream);

    dim3 grid((n_x + TPB - 1) / TPB, (n_obs + CH - 1) / CH);
    matern_partial<<<grid, TPB, 0, stream>>>(xobs, x, a0, a1, tfl, rls,
                                             rngo, rngx, f01, n_obs, n_x);

    combine_out<<<(n_x + 255) / 256, 256, 0, stream>>>(w, f01, (float*)d_out, n_x);
}

// Round 2
// 107.539 us; speedup vs baseline: 1.2218x; 1.2218x over previous
//
#include <hip/hip_runtime.h>
#include <math.h>

#define TPB 256
#define CH  64

typedef float f2 __attribute__((ext_vector_type(2)));

// ---------------------------------------------------------------------------
// Kernel 1: partial contraction. Each thread owns one column j of K.
// Block (bx, by) processes j-tile bx and obs-chunk by, accumulating
//   s0 = sum_i alpha0[i] * M(i,j),  s1 = sum_i alpha1[i] * M(i,j)
// per domain segment (transfer factor hoisted), then atomicAdds into f01.
// ---------------------------------------------------------------------------
__global__ __launch_bounds__(TPB, 4) void matern_partial(
    const float* __restrict__ xobs, const float* __restrict__ x,
    const float* __restrict__ alpha0, const float* __restrict__ alpha1,
    const float* __restrict__ tfl, const float* __restrict__ rawls,
    const int* __restrict__ rngo, const int* __restrict__ rngx,
    float* __restrict__ f01, int n_obs, int n_x)
{
    __shared__ float  s_xo[CH][16];   // scaled xobs rows
    __shared__ float4 s_meta[CH];     // {|xo|^2, alpha0, alpha1, 0}

    const int tid = threadIdx.x;
    const int j   = blockIdx.x * TPB + tid;
    const int c0  = blockIdx.y * CH;
    const int c1  = min(c0 + CH, n_obs);
    const int clen = c1 - c0;

    // lengthscale = softplus(raw)
    const float r      = rawls[0];
    const float ls     = fmaxf(r, 0.0f) + log1pf(__expf(-fabsf(r)));
    const float inv_ls = 1.0f / ls;

    // ---- stage scaled xobs chunk into LDS (coalesced) ----
    for (int idx = tid; idx < clen * 16; idx += TPB) {
        const int ii = idx >> 4, k = idx & 15;
        s_xo[ii][k] = xobs[(c0 + ii) * 16 + k] * inv_ls;
    }
    __syncthreads();
    // ---- per-row norm + alphas ----
    for (int ii = tid; ii < clen; ii += TPB) {
        float s = 0.f;
        #pragma unroll
        for (int k = 0; k < 16; ++k) { const float v = s_xo[ii][k]; s = fmaf(v, v, s); }
        s_meta[ii] = make_float4(s, alpha0[c0 + ii], alpha1[c0 + ii], 0.f);
    }
    __syncthreads();

    // ---- per-thread column data: packed float2 pairs ----
    const bool active = (j < n_x);
    const int  jj     = active ? j : 0;
    f2 xj2[8];
    float nxj = 0.f;
    #pragma unroll
    for (int k = 0; k < 8; ++k) {
        const float a = x[jj * 16 + 2 * k]     * inv_ls;
        const float b = x[jj * 16 + 2 * k + 1] * inv_ls;
        xj2[k] = f2{a, b};
        nxj = fmaf(a, a, fmaf(b, b, nxj));
    }

    // transfer factor row for this column's domain
    const float t0 = 1.f / (1.f + __expf(-tfl[0]));   // F[0][1]
    const float t1 = 1.f / (1.f + __expf(-tfl[1]));   // F[0][2]
    const float t2 = 1.f / (1.f + __expf(-tfl[2]));   // F[1][2]
    const int dxj = (jj >= rngx[2] ? 1 : 0) + (jj >= rngx[4] ? 1 : 0);
    const float fd0 = (dxj == 0) ? 1.f : ((dxj == 1) ? t0 : t1);
    const float fd1 = (dxj == 0) ? t0  : ((dxj == 1) ? 1.f : t2);
    const float fd2 = (dxj == 0) ? t1  : ((dxj == 1) ? t2  : 1.f);

    const float S5  = 2.2360679774997896f;   // sqrt(5)
    const float C53 = 5.0f / 3.0f;

    float acc0 = 0.f, acc1 = 0.f;

    #pragma unroll
    for (int dom = 0; dom < 3; ++dom) {
        const int ds = max(c0, rngo[dom * 2 + 0]);
        const int de = min(c1, rngo[dom * 2 + 1]);
        float s0 = 0.f, s1 = 0.f;
        #pragma unroll 4
        for (int i = ds; i < de; ++i) {
            const int ii = i - c0;
            const float4* xr = (const float4*)&s_xo[ii][0];   // uniform-addr b128 reads
            const float4 P0 = xr[0], P1 = xr[1], P2 = xr[2], P3 = xr[3];
            const float4 meta = s_meta[ii];

            // packed-fp32 dot: 8 v_pk_fma_f32 in two independent chains
            f2 d2 = xj2[0] * f2{P0.x, P0.y};
            f2 e2 = xj2[1] * f2{P0.z, P0.w};
            d2 = xj2[2] * f2{P1.x, P1.y} + d2;
            e2 = xj2[3] * f2{P1.z, P1.w} + e2;
            d2 = xj2[4] * f2{P2.x, P2.y} + d2;
            e2 = xj2[5] * f2{P2.z, P2.w} + e2;
            d2 = xj2[6] * f2{P3.x, P3.y} + d2;
            e2 = xj2[7] * f2{P3.z, P3.w} + e2;
            const float dot = (d2.x + d2.y) + (e2.x + e2.y);

            float sq = fmaf(-2.f, dot, meta.x + nxj);
            sq = fmaxf(sq, 1e-12f);
            const float d    = sq * __frsqrt_rn(sq);   // v_rsq + v_mul (no IEEE sqrt seq)
            const float s5d  = S5 * d;
            const float poly = fmaf(C53, sq, 1.0f + s5d);
            const float e    = __expf(-s5d);
            const float m    = poly * e;
            s0 = fmaf(meta.y, m, s0);
            s1 = fmaf(meta.z, m, s1);
        }
        const float fd = (dom == 0) ? fd0 : ((dom == 1) ? fd1 : fd2);
        acc0 = fmaf(fd, s0, acc0);
        acc1 = fmaf(fd, s1, acc1);
    }

    if (active) {
        atomicAdd(&f01[j], acc0);
        atomicAdd(&f01[n_x + j], acc1);
    }
}

// ---------------------------------------------------------------------------
// Kernel 2: out[j] = w[j]*f0[j] + (1-w[j])*f1[j]
// ---------------------------------------------------------------------------
__global__ void combine_out(const float* __restrict__ w,
                            const float* __restrict__ f01,
                            float* __restrict__ out, int n_x)
{
    const int j = blockIdx.x * 256 + threadIdx.x;
    if (j < n_x) {
        const float wv = w[j];
        out[j] = wv * f01[j] + (1.f - wv) * f01[n_x + j];
    }
}

extern "C" void kernel_launch(void* const* d_in, const int* in_sizes, int n_in,
                              void* d_out, int out_size, void* d_ws, size_t ws_size,
                              hipStream_t stream)
{
    const float* xobs = (const float*)d_in[0];
    const float* x    = (const float*)d_in[1];
    const float* w    = (const float*)d_in[2];
    const float* a0   = (const float*)d_in[3];
    const float* a1   = (const float*)d_in[4];
    const float* tfl  = (const float*)d_in[5];
    const float* rls  = (const float*)d_in[6];
    const int*   rngo = (const int*)d_in[7];
    const int*   rngx = (const int*)d_in[8];

    const int n_obs = in_sizes[0] / 16;
    const int n_x   = in_sizes[1] / 16;

    float* f01 = (float*)d_ws;   // [2][n_x] partial sums
    hipMemsetAsync(f01, 0, sizeof(float) * 2 * (size_t)n_x, stream);

    dim3 grid((n_x + TPB - 1) / TPB, (n_obs + CH - 1) / CH);
    matern_partial<<<grid, TPB, 0, stream>>>(xobs, x, a0, a1, tfl, rls,
                                             rngo, rngx, f01, n_obs, n_x);

    combine_out<<<(n_x + 255) / 256, 256, 0, stream>>>(w, f01, (float*)d_out, n_x);
}